// Round 15
// baseline (282.165 us; speedup 1.0000x reference)
//
#include <hip/hip_runtime.h>
#include <math.h>

// EntNet forward on MI355X.
// Sizes: VOC=32000, MEM=128, NSLOTS=20, NSENT=128, MAXLEN=32, QLEN=16, ANSLEN=8, B=64
//
// R27 = 16x16-tile re-partition of the scan (single barrier per step).
// Wave (rg=wave>>1, cg=wave&1) owns rows rg*16..+15 x cols cg*64..+63 via
// 4x4 mfma_f32_16x16x32_bf16 tiles (layout HW-verified in R19):
//   A/B: row/col = lane&15, k = (lane>>4)*8+e + kc*32
//   C:   col = lane&15 (n), row = (lane>>4)*4+reg (b)
// Wins vs R26 (157.7us):
//  - A-frag reads 8->4 b128/wave, zero cross-wave duplication (768->384cy)
//    while KEEPING 8 waves / 2 per SIMD (R25 lesson).
//  - gate is wave-local: the 4 kg-lanes of row r hold the full state row in
//    the A-frags -> in-register dot2, xor16/xor32 reduce, wave-local LDS
//    bounce (lgkmcnt only, no barrier). g_l cross-wave round trip deleted.
//  - AB double-buffered (+wred double-buffered) -> ONE lgkm-only barrier
//    per step instead of two.
// Register peak ~210 < 256-per-wave budget at 2 waves/SIMD (R21 lesson);
// launch_bounds(512,2) caps the allocator. Global patterns unchanged (R20).

typedef __attribute__((ext_vector_type(8)))  short bf16x8;
typedef __attribute__((ext_vector_type(4)))  float f32x4;
typedef __attribute__((ext_vector_type(2)))  float f32x2;

__device__ __forceinline__ unsigned short f2bh(float x) {   // f32 -> bf16 RNE
    unsigned int u = __float_as_uint(x);
    u += 0x7FFFu + ((u >> 16) & 1u);
    return (unsigned short)(u >> 16);
}
// pack two f32 -> u32 of two bf16 (truncation; fp32 recurrence carries precision)
__device__ __forceinline__ unsigned int packtr(float lo, float hi) {
    return (__float_as_uint(lo) >> 16) | (__float_as_uint(hi) & 0xFFFF0000u);
}
__device__ __forceinline__ float blo(unsigned int w) { return __uint_as_float(w << 16); }
__device__ __forceinline__ float bhi(unsigned int w) { return __uint_as_float(w & 0xFFFF0000u); }

// packed-f32 helpers (lower to v_pk_* on gfx90a+/gfx950)
__device__ __forceinline__ f32x2 pkfma(f32x2 a, f32x2 b, f32x2 c) {
    return __builtin_elementwise_fma(a, b, c);
}
__device__ __forceinline__ f32x2 pkmax0(f32x2 a) {
    return __builtin_elementwise_max(a, (f32x2){0.f, 0.f});
}

#if __has_builtin(__builtin_amdgcn_fdot2_f32_bf16)
typedef __attribute__((ext_vector_type(2))) __bf16 bf16x2v;
__device__ __forceinline__ float dot2bf(unsigned int a, unsigned int b, float c) {
    return __builtin_amdgcn_fdot2_f32_bf16(
        __builtin_bit_cast(bf16x2v, a), __builtin_bit_cast(bf16x2v, b), c, false);
}
#else
__device__ __forceinline__ float dot2bf(unsigned int a, unsigned int b, float c) {
    return fmaf(bhi(a), bhi(b), fmaf(blo(a), blo(b), c));
}
#endif

// DPP add helper: x += dpp_move(x) with 0-fill (bound_ctrl=true).
// CTRL: row_shr:N = 0x110+N, row_bcast:15 = 0x142, row_bcast:31 = 0x143.
template<int CTRL>
__device__ __forceinline__ float dpp_add0(float x) {
    int y = __builtin_amdgcn_update_dpp(0, __float_as_int(x), CTRL, 0xF, 0xF, true);
    return x + __int_as_float(y);
}
// neighbor value via quad_perm xor1 (lane^1)
__device__ __forceinline__ float dpp_xor1_move(float x) {
    int y = __builtin_amdgcn_update_dpp(0, __float_as_int(x), 0xB1, 0xF, 0xF, true);
    return __int_as_float(y);
}

// LDS-only workgroup barrier: waits own DS ops, does NOT drain vmcnt, so
// prefetched global loads (private register results) stay in flight.
#define LDS_BARRIER() do {                                   \
    asm volatile("s_waitcnt lgkmcnt(0)" ::: "memory");       \
    __builtin_amdgcn_s_barrier();                            \
    asm volatile("" ::: "memory");                           \
} while (0)

// ---------------------------------------------------------------- prep
__global__ __launch_bounds__(128) void prep_kernel(
    const int* __restrict__ ids, const int* __restrict__ ques, const int* __restrict__ ans,
    const float* __restrict__ E, const float* __restrict__ Ww, const float* __restrict__ Wb,
    const float* __restrict__ Vw, const float* __restrict__ Vb, const float* __restrict__ skeys,
    unsigned short* __restrict__ sT2, float* __restrict__ WsT, float* __restrict__ vkey,
    float* __restrict__ qv, float* __restrict__ a1v, float* __restrict__ a2v,
    float* __restrict__ SK)
{
    const int bi  = blockIdx.x;
    const int tid = threadIdx.x;   // 128
    __shared__ float s_l[8][132];
    __shared__ float sk_l[20 * 132];
    __shared__ float k_l[128];
    if (bi < 1024) {
        const int b = bi >> 4;
        const int g = bi & 15;
        for (int r = tid; r < 2560; r += 128) sk_l[(r >> 7) * 132 + (r & 127)] = skeys[r];
        for (int tt = 0; tt < 8; ++tt) {
            const int t     = g * 8 + tt;
            const int token = ids[b * 4096 + t];
            const float v   = E[token * 128 + tid];
            s_l[tt][tid] = v;
            sT2[(t * 64 + b) * 128 + tid] = f2bh(v);   // bf16 plane (t, b, m)
        }
        __syncthreads();
        // Ws rows
        float acc[8];
        const float wbn = Wb[tid];
        #pragma unroll
        for (int i = 0; i < 8; ++i) acc[i] = wbn;
        const float4* wrow = (const float4*)(Ww + tid * 128);
        for (int m4 = 0; m4 < 32; ++m4) {
            const float4 w = wrow[m4];
            #pragma unroll
            for (int tt = 0; tt < 8; ++tt) {
                acc[tt] += s_l[tt][m4*4+0]*w.x + s_l[tt][m4*4+1]*w.y
                         + s_l[tt][m4*4+2]*w.z + s_l[tt][m4*4+3]*w.w;
            }
        }
        for (int tt = 0; tt < 8; ++tt)
            WsT[((g*8+tt) * 64 + b) * 128 + tid] = acc[tt];     // layout (t, b, n)
        // SK[j][t][b] = dot(s_t[b], skeys[j])  (gate key-dot, hoisted from scan)
        for (int idx = tid; idx < 160; idx += 128) {
            const int tt = idx / 20;
            const int jj = idx - tt * 20;
            float d = 0.f;
            for (int m = 0; m < 128; ++m) d += s_l[tt][m] * sk_l[jj * 132 + m];
            SK[(jj * 128 + (g*8 + tt)) * 64 + b] = d;
        }
    } else if (bi < 1044) {
        const int j = bi - 1024;
        k_l[tid] = skeys[j * 128 + tid];
        __syncthreads();
        float acc = Vb[tid];
        const float4* vrow = (const float4*)(Vw + tid * 128);
        for (int m4 = 0; m4 < 32; ++m4) {
            const float4 w = vrow[m4];
            acc += k_l[m4*4]*w.x + k_l[m4*4+1]*w.y + k_l[m4*4+2]*w.z + k_l[m4*4+3]*w.w;
        }
        vkey[j * 128 + tid] = acc;
    } else {
        const int b = bi - 1044;
        float sq = 0.f, s1 = 0.f, s2 = 0.f;
        for (int i = 0; i < 16; ++i) sq += E[ques[b*16+i] * 128 + tid];
        for (int i = 0; i < 8;  ++i) s1 += E[ans[(b*8+i)*2+0] * 128 + tid];
        for (int i = 0; i < 8;  ++i) s2 += E[ans[(b*8+i)*2+1] * 128 + tid];
        qv [b*128+tid] = sq * (1.f/16.f);
        a1v[b*128+tid] = s1 * 0.125f;
        a2v[b*128+tid] = s2 * 0.125f;
    }
}

// ---------------------------------------------------------------- scan (MFMA 16x16, bf16 state)
// One block per slot j. 512 threads = 8 waves, 2 waves/SIMD.
// Wave (rg = wave>>1, cg = wave&1) owns rows rg*16..+15 x cols cg*64..+63
// (4 tiles of 16x16). Single lgkm-only barrier per step; AB and wred
// double-buffered. Gate computed in-wave from the A-fragments.
__global__ __launch_bounds__(512, 2) void scan_kernel(
    const unsigned short* __restrict__ sT2, const float* __restrict__ WsT,
    const float* __restrict__ vkey, const float* __restrict__ Uw,
    const float* __restrict__ Ub, const float* __restrict__ SK,
    float* __restrict__ h_out)
{
    __shared__ unsigned short AB0[64 * 136];  // bf16 state buffers, stride 136
    __shared__ unsigned short AB1[64 * 136];
    __shared__ float g_w[8][16];              // per-wave gate values
    __shared__ float wredA[8], wredB[8];      // double-buffered norm partials

    const int j    = blockIdx.x;
    const int tid  = threadIdx.x;        // 512
    const int wave = tid >> 6;           // 0..7
    const int lane = tid & 63;
    const int c16  = lane & 15;          // n within 16-tile / gate row within rg
    const int kg   = lane >> 4;          // 0..3 (k-group)
    const int rg   = wave >> 1;          // row group: b rows rg*16..+15
    const int cg   = wave & 1;           // col group: n cols cg*64..+63
    const int brow_a = rg * 16 + c16;    // A-frag / gate row this lane loads
    const bool evenl = ((c16 & 1) == 0); // column-pair parity

    // ---- one-time: Uw B-fragments for 4 tiles x 4 kc (bf16 RNE) ----
    bf16x8 b_h[4][4];
    #pragma unroll
    for (int tl = 0; tl < 4; ++tl) {
        const int n = cg * 64 + tl * 16 + c16;
        #pragma unroll
        for (int kc = 0; kc < 4; ++kc) {
            const float4* src = (const float4*)(Uw + n * 128 + kc * 32 + kg * 8);
            const float4 v0 = src[0], v1 = src[1];
            const float xs[8] = {v0.x,v0.y,v0.z,v0.w, v1.x,v1.y,v1.z,v1.w};
            #pragma unroll
            for (int e = 0; e < 8; ++e) b_h[tl][kc][e] = (short)f2bh(xs[e]);
        }
    }
    for (int i = tid; i < 64 * 136 / 2; i += 512) {
        ((unsigned int*)AB0)[i] = 0u;
        ((unsigned int*)AB1)[i] = 0u;
    }

    // ---- per-thread bias + invariant offsets ----
    float ubv[4];
    #pragma unroll
    for (int tl = 0; tl < 4; ++tl) {
        const int n = cg * 64 + tl * 16 + c16;
        ubv[tl] = Ub[n] + vkey[j * 128 + n];
    }
    unsigned woff[16];    // [tl*4 + reg]
    #pragma unroll
    for (int tl = 0; tl < 4; ++tl)
        #pragma unroll
        for (int reg = 0; reg < 4; ++reg) {
            const int b = rg * 16 + kg * 4 + reg;
            const int n = cg * 64 + tl * 16 + c16;
            woff[tl * 4 + reg] = (unsigned)((b * 128 + n) * 4);
        }
    const unsigned sfoff = (unsigned)(brow_a * 256 + kg * 16);   // bytes into sT2 plane
    const unsigned skoff = (unsigned)(brow_a * 4);
    const char* SKj = (const char*)SK + (size_t)j * 32768;
    // paired state-write bases (u32 units), per destination buffer
    const int wbidx = (rg*16 + kg*4 + (evenl ? 0 : 2)) * 68 + cg*32 + (c16 >> 1);
    unsigned* const wb0 = (unsigned*)AB0 + wbidx;   // writes land here when dst=AB0
    unsigned* const wb1 = (unsigned*)AB1 + wbidx;

    // fp32 recurrence state: xprev2[tl*2+rp] = {x[2rp][tl], x[2rp+1][tl]}
    f32x2 xprev2[8];
    #pragma unroll
    for (int p = 0; p < 8; ++p) xprev2[p] = (f32x2){0.f, 0.f};
#define XV(reg, tl) ((reg) & 1 ? xprev2[(tl)*2 + ((reg)>>1)].y : xprev2[(tl)*2 + ((reg)>>1)].x)

    // ---- ping-pong prefetched globals ----
    uint4 sfA[4], sfB[4];
    float skvA, skvB;
    float wsv[16];
    {
        const char* pS = (const char*)sT2 + sfoff;
        #pragma unroll
        for (int kc = 0; kc < 4; ++kc) sfA[kc] = *(const uint4*)(pS + kc * 64);
        skvA = *(const float*)(SKj + skoff);
        const char* pW = (const char*)WsT;
        #pragma unroll
        for (int r = 0; r < 16; ++r) wsv[r] = *(const float*)(pW + woff[r]);
    }
    __syncthreads();

    float inv_s = 1.f;                   // true mem = inv_s * bf16(state)

#define SCAN_STEP(T_CUR, ABc, WB, WRED, SFc, SKVc, SFn, SKVn)                  \
    {                                                                          \
        const int tn = (T_CUR < 127) ? (T_CUR) + 1 : 127;                      \
        /* prefetch t+1 sf/skv at TOP: full-step vmcnt cover */                \
        {                                                                      \
            const char* pS = (const char*)sT2 + (size_t)tn * 16384 + sfoff;    \
            _Pragma("unroll")                                                  \
            for (int kc = 0; kc < 4; ++kc) SFn[kc] = *(const uint4*)(pS + kc * 64); \
            SKVn = *(const float*)(SKj + (size_t)tn * 256 + skoff);            \
        }                                                                      \
        /* A-frag reads: 4x b128, rows owned zero-duplicated per wave-pair */  \
        uint4 w[4];                                                            \
        {                                                                      \
            const unsigned short* ar = ABc + brow_a * 136 + kg * 8;            \
            _Pragma("unroll")                                                  \
            for (int kc = 0; kc < 4; ++kc) w[kc] = *(const uint4*)(ar + kc * 32); \
        }                                                                      \
        /* MFMA: 4 tiles x 4 kc, tile-interleaved (4 indep 4-deep chains) */   \
        f32x4 acc[4];                                                          \
        _Pragma("unroll")                                                      \
        for (int tl = 0; tl < 4; ++tl) acc[tl] = (f32x4){0.f,0.f,0.f,0.f};     \
        _Pragma("unroll")                                                      \
        for (int kc = 0; kc < 4; ++kc) {                                       \
            const bf16x8 a = __builtin_bit_cast(bf16x8, w[kc]);                \
            _Pragma("unroll")                                                  \
            for (int tl = 0; tl < 4; ++tl)                                     \
                acc[tl] = __builtin_amdgcn_mfma_f32_16x16x32_bf16(a, b_h[tl][kc], acc[tl], 0, 0, 0); \
        }                                                                      \
        /* gate: in-register dot from the SAME frags; wave-local publish */    \
        {                                                                      \
            float d0 = dot2bf(w[0].x, SFc[0].x, 0.f);                          \
            float d1 = dot2bf(w[0].y, SFc[0].y, 0.f);                          \
            float d2 = dot2bf(w[0].z, SFc[0].z, 0.f);                          \
            float d3 = dot2bf(w[0].w, SFc[0].w, 0.f);                          \
            _Pragma("unroll")                                                  \
            for (int kc = 1; kc < 4; ++kc) {                                   \
                d0 = dot2bf(w[kc].x, SFc[kc].x, d0);                           \
                d1 = dot2bf(w[kc].y, SFc[kc].y, d1);                           \
                d2 = dot2bf(w[kc].z, SFc[kc].z, d2);                           \
                d3 = dot2bf(w[kc].w, SFc[kc].w, d3);                           \
            }                                                                  \
            float dd = (d0 + d1) + (d2 + d3);                                  \
            dd += __shfl_xor(dd, 16, 64);                                      \
            dd += __shfl_xor(dd, 32, 64);                                      \
            if (kg == 0) {                                                     \
                const float e = __expf(-(inv_s * dd + SKVc));                  \
                g_w[wave][c16] = __builtin_amdgcn_rcpf(1.f + e);               \
            }                                                                  \
        }                                                                      \
        asm volatile("s_waitcnt lgkmcnt(0)" ::: "memory");   /* g_w visible (wave-local) */ \
        const float4 g4 = *(const float4*)(&g_w[wave][kg * 4]);                \
        /* update: x = inv*xprev + g*relu(inv*acc + ws+ub), packed pairs */    \
        const f32x2 inv2 = {inv_s, inv_s};                                     \
        f32x2 ssqv = {0.f, 0.f};                                               \
        _Pragma("unroll")                                                      \
        for (int tl = 0; tl < 4; ++tl) {                                       \
            const f32x2 ub2 = {ubv[tl], ubv[tl]};                              \
            _Pragma("unroll")                                                  \
            for (int rp = 0; rp < 2; ++rp) {                                   \
                const int p = tl * 2 + rp;                                     \
                const f32x2 am = {acc[tl][2*rp], acc[tl][2*rp+1]};             \
                const f32x2 wu = (f32x2){wsv[tl*4+2*rp], wsv[tl*4+2*rp+1]} + ub2; \
                f32x2 hr = pkfma(inv2, am, wu);                                \
                hr = pkmax0(hr);                                               \
                const f32x2 gg = rp ? (f32x2){g4.z, g4.w} : (f32x2){g4.x, g4.y}; \
                const f32x2 x = pkfma(inv2, xprev2[p], hr * gg);               \
                xprev2[p] = x;                                                 \
                ssqv = pkfma(x, x, ssqv);                                      \
            }                                                                  \
        }                                                                      \
        /* paired state write-back into the OTHER buffer: 8x ds_write_b32 */   \
        _Pragma("unroll")                                                      \
        for (int tl = 0; tl < 4; ++tl) {                                       \
            const float s0 = dpp_xor1_move(XV(0, tl));                         \
            const float s1 = dpp_xor1_move(XV(1, tl));                         \
            const float s2 = dpp_xor1_move(XV(2, tl));                         \
            const float s3 = dpp_xor1_move(XV(3, tl));                         \
            const float loA = evenl ? XV(0, tl) : s2;                          \
            const float hiA = evenl ? s0        : XV(2, tl);                   \
            const float loB = evenl ? XV(1, tl) : s3;                          \
            const float hiB = evenl ? s1        : XV(3, tl);                   \
            WB[tl * 8]      = packtr(loA, hiA);                                \
            WB[68 + tl * 8] = packtr(loB, hiB);                                \
        }                                                                      \
        /* wsv refetch for t+1 (use point is next update: ~1-step cover) */    \
        {                                                                      \
            const char* pW = (const char*)WsT + (size_t)tn * 32768;            \
            _Pragma("unroll")                                                  \
            for (int r = 0; r < 16; ++r)                                       \
                wsv[r] = *(const float*)(pW + woff[r]);                        \
        }                                                                      \
        /* ssq reduce: 6-op DPP chain, lane 63 holds the wave total */         \
        float ssq = ssqv.x + ssqv.y;                                           \
        ssq = dpp_add0<0x111>(ssq);                                            \
        ssq = dpp_add0<0x112>(ssq);                                            \
        ssq = dpp_add0<0x114>(ssq);                                            \
        ssq = dpp_add0<0x118>(ssq);                                            \
        ssq = dpp_add0<0x142>(ssq);                                            \
        ssq = dpp_add0<0x143>(ssq);                                            \
        if (lane == 63) WRED[wave] = ssq;                                      \
        LDS_BARRIER();   /* SINGLE barrier: state + wred visible */            \
        const float4 q0 = *(const float4*)(WRED);                              \
        const float4 q1 = *(const float4*)(WRED + 4);                          \
        const float4 qs = q0 + q1;                                             \
        inv_s = __builtin_amdgcn_rsqf((qs.x + qs.y) + (qs.z + qs.w));          \
    }

    for (int t = 0; t < 128; t += 2) {
        SCAN_STEP(t,     AB0, wb1, wredA, sfA, skvA, sfB, skvB)   // read AB0, write AB1
        SCAN_STEP(t + 1, AB1, wb0, wredB, sfB, skvB, sfA, skvA)   // read AB1, write AB0
    }
#undef SCAN_STEP

    // ---- h = inv * state (fp32 path), layout (b, j, m) ----
    #pragma unroll
    for (int tl = 0; tl < 4; ++tl)
        #pragma unroll
        for (int reg = 0; reg < 4; ++reg) {
            const int b = rg * 16 + kg * 4 + reg;
            const int n = cg * 64 + tl * 16 + c16;
            h_out[((size_t)b * 20 + j) * 128 + n] = inv_s * XV(reg, tl);
        }
#undef XV
}

// ---------------------------------------------------------------- final
__global__ __launch_bounds__(128) void final_kernel(
    const float* __restrict__ h, const float* __restrict__ qv,
    const float* __restrict__ a1v, const float* __restrict__ a2v,
    const float* __restrict__ Hw, const float* __restrict__ Hb,
    float* __restrict__ out)
{
    const int b   = blockIdx.x;
    const int tid = threadIdx.x;    // 128
    __shared__ float hb[20][128];
    __shared__ float ql[128];
    __shared__ float ul[128];
    __shared__ float pl[20];
    __shared__ float lgt[20];
    __shared__ float red1[2], red2[2];

    for (int jj = 0; jj < 20; ++jj) hb[jj][tid] = h[(b*20+jj)*128 + tid];
    ql[tid] = qv[b*128 + tid];
    __syncthreads();
    if (tid < 20) {
        float d = 0.f;
        for (int m = 0; m < 128; ++m) d += hb[tid][m] * ql[m];
        lgt[tid] = d;
    }
    __syncthreads();
    if (tid == 0) {
        float mx = lgt[0];
        for (int jj = 1; jj < 20; ++jj) mx = fmaxf(mx, lgt[jj]);
        float s = 0.f;
        for (int jj = 0; jj < 20; ++jj) { const float e = expf(lgt[jj]-mx); pl[jj] = e; s += e; }
        const float is = 1.f / s;
        for (int jj = 0; jj < 20; ++jj) pl[jj] *= is;
    }
    __syncthreads();
    float u = 0.f;
    for (int jj = 0; jj < 20; ++jj) u += pl[jj] * hb[jj][tid];
    ul[tid] = u;
    __syncthreads();
    float acc = ql[tid] + Hb[tid];
    const float4* hwr = (const float4*)(Hw + tid*128);
    for (int m4 = 0; m4 < 32; ++m4) {
        const float4 w = hwr[m4];
        acc += ul[m4*4]*w.x + ul[m4*4+1]*w.y + ul[m4*4+2]*w.z + ul[m4*4+3]*w.w;
    }
    const float r  = fmaxf(acc, 0.f);
    float y1 = r * a1v[b*128+tid];
    float y2 = r * a2v[b*128+tid];
    #pragma unroll
    for (int mask = 1; mask < 64; mask <<= 1) {
        y1 += __shfl_xor(y1, mask, 64);
        y2 += __shfl_xor(y2, mask, 64);
    }
    if ((tid & 63) == 0) { red1[tid>>6] = y1; red2[tid>>6] = y2; }
    __syncthreads();
    if (tid == 0) {
        const float z1 = red1[0] + red1[1];
        const float z2 = red2[0] + red2[1];
        const float mx = fmaxf(z1, z2);
        const float e1 = expf(z1-mx), e2 = expf(z2-mx);
        const float s  = e1 + e2;
        out[b*2+0] = e1 / s;
        out[b*2+1] = e2 / s;
    }
}

// ---------------------------------------------------------------- launch
extern "C" void kernel_launch(void* const* d_in, const int* in_sizes, int n_in,
                              void* d_out, int out_size, void* d_ws, size_t ws_size,
                              hipStream_t stream)
{
    const int*   ids  = (const int*)  d_in[0];
    const int*   ques = (const int*)  d_in[1];
    const int*   ans  = (const int*)  d_in[2];
    const float* E    = (const float*)d_in[3];
    const float* Uw   = (const float*)d_in[4];
    const float* Ubv  = (const float*)d_in[5];
    const float* Vw   = (const float*)d_in[6];
    const float* Vb   = (const float*)d_in[7];
    const float* Ww   = (const float*)d_in[8];
    const float* Wb   = (const float*)d_in[9];
    const float* sk   = (const float*)d_in[10];
    const float* Hw   = (const float*)d_in[11];
    const float* Hb   = (const float*)d_in[12];

    // workspace (floats): sT2 bf16[1048576] = 524288 floats | WsT 1048576 |
    //   vkey 2560 | qv/a1v/a2v 3*8192 | h 163840 | SK 163840   (~7.7 MB)
    float* ws   = (float*)d_ws;
    unsigned short* sT2 = (unsigned short*)ws;        // 1048576 ushort = 524288 floats
    float* WsT  = ws    + 524288;
    float* vkey = WsT   + 1048576;
    float* qv   = vkey  + 2560;
    float* a1v  = qv    + 8192;
    float* a2v  = a1v   + 8192;
    float* h    = a2v   + 8192;
    float* SK   = h     + 163840;

    prep_kernel<<<1108, 128, 0, stream>>>(ids, ques, ans, E, Ww, Wb, Vw, Vb, sk,
                                          sT2, WsT, vkey, qv, a1v, a2v, SK);
    scan_kernel<<<20, 512, 0, stream>>>(sT2, WsT, vkey, Uw, Ubv, SK, h);
    final_kernel<<<64, 128, 0, stream>>>(h, qv, a1v, a2v, Hw, Hb, (float*)d_out);
}

// Round 16
// 262.089 us; speedup vs baseline: 1.0766x; 1.0766x over previous
//
#include <hip/hip_runtime.h>
#include <math.h>

// EntNet forward on MI355X.
// Sizes: VOC=32000, MEM=128, NSLOTS=20, NSENT=128, MAXLEN=32, QLEN=16, ANSLEN=8, B=64
//
// R28 = restore R26/R24c (measured best: scan 157.7us, total 260.5us).
// R27 (16x16 tiles, single barrier, wave-local gate) was the SEVENTH
// structural variant to lose (179.7us): doubled MFMA issue, bpermute
// shuffles on the gate path, and the wave-local lgkm wait re-serialized
// what the barrier removal saved. The scan is a latency-bound serial
// recurrence: 20 blocks (fixed by the per-slot norm coupling all (b,m)
// per step), 128 sequential steps, chain latency x 2-wave/SIMD hiding.
// The incremental line (R17 full-cover prefetch -> R22 DPP reductions ->
// R23 paired writes + dot2 gate -> R24c pk-f32 update) is the optimum.

typedef __attribute__((ext_vector_type(8)))  short bf16x8;
typedef __attribute__((ext_vector_type(16))) float f32x16;
typedef __attribute__((ext_vector_type(2)))  float f32x2;

__device__ __forceinline__ unsigned short f2bh(float x) {   // f32 -> bf16 RNE
    unsigned int u = __float_as_uint(x);
    u += 0x7FFFu + ((u >> 16) & 1u);
    return (unsigned short)(u >> 16);
}
// pack two f32 -> u32 of two bf16 (truncation; fp32 recurrence carries precision)
__device__ __forceinline__ unsigned int packtr(float lo, float hi) {
    return (__float_as_uint(lo) >> 16) | (__float_as_uint(hi) & 0xFFFF0000u);
}
__device__ __forceinline__ float blo(unsigned int w) { return __uint_as_float(w << 16); }
__device__ __forceinline__ float bhi(unsigned int w) { return __uint_as_float(w & 0xFFFF0000u); }

// packed-f32 helpers (lower to v_pk_* on gfx90a+/gfx950)
__device__ __forceinline__ f32x2 pkfma(f32x2 a, f32x2 b, f32x2 c) {
    return __builtin_elementwise_fma(a, b, c);
}
__device__ __forceinline__ f32x2 pkmax0(f32x2 a) {
    return __builtin_elementwise_max(a, (f32x2){0.f, 0.f});
}

#if __has_builtin(__builtin_amdgcn_fdot2_f32_bf16)
typedef __attribute__((ext_vector_type(2))) __bf16 bf16x2v;
__device__ __forceinline__ float dot2bf(unsigned int a, unsigned int b, float c) {
    return __builtin_amdgcn_fdot2_f32_bf16(
        __builtin_bit_cast(bf16x2v, a), __builtin_bit_cast(bf16x2v, b), c, false);
}
#else
__device__ __forceinline__ float dot2bf(unsigned int a, unsigned int b, float c) {
    return fmaf(bhi(a), bhi(b), fmaf(blo(a), blo(b), c));
}
#endif

// DPP add helper: x += dpp_move(x) with 0-fill (bound_ctrl=true).
// CTRL: row_shr:N = 0x110+N, row_bcast:15 = 0x142, row_bcast:31 = 0x143.
template<int CTRL>
__device__ __forceinline__ float dpp_add0(float x) {
    int y = __builtin_amdgcn_update_dpp(0, __float_as_int(x), CTRL, 0xF, 0xF, true);
    return x + __int_as_float(y);
}
// neighbor value via quad_perm xor1 (lane^1)
__device__ __forceinline__ float dpp_xor1_move(float x) {
    int y = __builtin_amdgcn_update_dpp(0, __float_as_int(x), 0xB1, 0xF, 0xF, true);
    return __int_as_float(y);
}

// LDS-only workgroup barrier: waits own DS ops, does NOT drain vmcnt, so
// prefetched global loads (private register results) stay in flight.
#define LDS_BARRIER() do {                                   \
    asm volatile("s_waitcnt lgkmcnt(0)" ::: "memory");       \
    __builtin_amdgcn_s_barrier();                            \
    asm volatile("" ::: "memory");                           \
} while (0)

// ---------------------------------------------------------------- prep
__global__ __launch_bounds__(128) void prep_kernel(
    const int* __restrict__ ids, const int* __restrict__ ques, const int* __restrict__ ans,
    const float* __restrict__ E, const float* __restrict__ Ww, const float* __restrict__ Wb,
    const float* __restrict__ Vw, const float* __restrict__ Vb, const float* __restrict__ skeys,
    unsigned short* __restrict__ sT2, float* __restrict__ WsT, float* __restrict__ vkey,
    float* __restrict__ qv, float* __restrict__ a1v, float* __restrict__ a2v,
    float* __restrict__ SK)
{
    const int bi  = blockIdx.x;
    const int tid = threadIdx.x;   // 128
    __shared__ float s_l[8][132];
    __shared__ float sk_l[20 * 132];
    __shared__ float k_l[128];
    if (bi < 1024) {
        const int b = bi >> 4;
        const int g = bi & 15;
        for (int r = tid; r < 2560; r += 128) sk_l[(r >> 7) * 132 + (r & 127)] = skeys[r];
        for (int tt = 0; tt < 8; ++tt) {
            const int t     = g * 8 + tt;
            const int token = ids[b * 4096 + t];
            const float v   = E[token * 128 + tid];
            s_l[tt][tid] = v;
            sT2[(t * 64 + b) * 128 + tid] = f2bh(v);   // bf16 plane (t, b, m)
        }
        __syncthreads();
        // Ws rows
        float acc[8];
        const float wbn = Wb[tid];
        #pragma unroll
        for (int i = 0; i < 8; ++i) acc[i] = wbn;
        const float4* wrow = (const float4*)(Ww + tid * 128);
        for (int m4 = 0; m4 < 32; ++m4) {
            const float4 w = wrow[m4];
            #pragma unroll
            for (int tt = 0; tt < 8; ++tt) {
                acc[tt] += s_l[tt][m4*4+0]*w.x + s_l[tt][m4*4+1]*w.y
                         + s_l[tt][m4*4+2]*w.z + s_l[tt][m4*4+3]*w.w;
            }
        }
        for (int tt = 0; tt < 8; ++tt)
            WsT[((g*8+tt) * 64 + b) * 128 + tid] = acc[tt];     // layout (t, b, n)
        // SK[j][t][b] = dot(s_t[b], skeys[j])  (gate key-dot, hoisted from scan)
        for (int idx = tid; idx < 160; idx += 128) {
            const int tt = idx / 20;
            const int jj = idx - tt * 20;
            float d = 0.f;
            for (int m = 0; m < 128; ++m) d += s_l[tt][m] * sk_l[jj * 132 + m];
            SK[(jj * 128 + (g*8 + tt)) * 64 + b] = d;
        }
    } else if (bi < 1044) {
        const int j = bi - 1024;
        k_l[tid] = skeys[j * 128 + tid];
        __syncthreads();
        float acc = Vb[tid];
        const float4* vrow = (const float4*)(Vw + tid * 128);
        for (int m4 = 0; m4 < 32; ++m4) {
            const float4 w = vrow[m4];
            acc += k_l[m4*4]*w.x + k_l[m4*4+1]*w.y + k_l[m4*4+2]*w.z + k_l[m4*4+3]*w.w;
        }
        vkey[j * 128 + tid] = acc;
    } else {
        const int b = bi - 1044;
        float sq = 0.f, s1 = 0.f, s2 = 0.f;
        for (int i = 0; i < 16; ++i) sq += E[ques[b*16+i] * 128 + tid];
        for (int i = 0; i < 8;  ++i) s1 += E[ans[(b*8+i)*2+0] * 128 + tid];
        for (int i = 0; i < 8;  ++i) s2 += E[ans[(b*8+i)*2+1] * 128 + tid];
        qv [b*128+tid] = sq * (1.f/16.f);
        a1v[b*128+tid] = s1 * 0.125f;
        a2v[b*128+tid] = s2 * 0.125f;
    }
}

// ---------------------------------------------------------------- scan (MFMA 32x32, bf16 state)
// One block per slot j. 512 threads = 8 waves, 2 waves/SIMD.
// Each wave owns ONE 32x32 C tile (bt2 = wave&1, nt2 = wave>>1).
// C/D layout [m74/m101]: col = lane&31, row = (reg&3)+8*(reg>>2)+4*(lane>>5).
// 2 lgkm-only barriers/step; sv/skv prefetch at step TOP (ping-pong regs,
// full-step vmcnt cover); wsv prefetch in update (~1-step cover).
// DPP reductions; paired b32 state writes; bf16 gate via dot2; pk-f32 update.
__global__ __launch_bounds__(512, 1) void scan_kernel(
    const unsigned short* __restrict__ sT2, const float* __restrict__ WsT,
    const float* __restrict__ vkey, const float* __restrict__ Uw,
    const float* __restrict__ Ub, const float* __restrict__ SK,
    float* __restrict__ h_out)
{
    __shared__ unsigned short AB[64 * 136];   // bf16 state, stride 136 (272B rows)
    __shared__ float g_l[64];
    __shared__ float wred[8];

    const int j    = blockIdx.x;
    const int tid  = threadIdx.x;        // 512
    const int wave = tid >> 6;           // 0..7
    const int lane = tid & 63;
    const int l32  = lane & 31;
    const int q    = lane >> 5;          // 0..1
    const int bt2  = wave & 1;           // b half
    const int nt2  = wave >> 1;          // n quarter
    const int n    = nt2 * 32 + l32;     // owned output column
    const int gb   = tid >> 3;           // gate: batch row 0..63
    const int gm   = (tid & 7) * 16;     // gate: m-slice (16 bf16)
    const bool evenl = ((l32 & 1) == 0); // column-pair parity

    // ---- one-time: weight fragments -> 32 VGPRs (single bf16 plane, RNE) ----
    bf16x8 b_h[8];
    {
        const int k0 = q * 8;
        #pragma unroll
        for (int kc = 0; kc < 8; ++kc) {
            const float4* src = (const float4*)(Uw + n * 128 + kc * 16 + k0);
            const float4 v0 = src[0], v1 = src[1];
            const float xs[8] = {v0.x,v0.y,v0.z,v0.w, v1.x,v1.y,v1.z,v1.w};
            #pragma unroll
            for (int e = 0; e < 8; ++e) b_h[kc][e] = (short)f2bh(xs[e]);
        }
    }
    for (int i = tid; i < 64 * 136 / 2; i += 512) ((unsigned int*)AB)[i] = 0u;
    const float ubv = Ub[n] + vkey[j * 128 + n];

    // ---- per-thread invariant load offsets (bytes), computed once ----
    unsigned woffB[16];
    #pragma unroll
    for (int r = 0; r < 16; ++r) {
        const int brow = bt2*32 + 4*q + (r & 3) + 8*(r >> 2);
        woffB[r] = (unsigned)((brow * 128 + n) * 4);
    }
    const unsigned soffB = (unsigned)((gb * 128 + gm) * 2);   // bf16 plane
    const unsigned koffB = (unsigned)(gb * 4);
    const char* SKj = (const char*)SK + (size_t)j * 32768;
    // paired state-write base: row = bt2*32 + 4q + parity*16, colpair byte = (n&~1)*2
    unsigned* const wdst = (unsigned*)((char*)AB
        + (bt2*32 + 4*q + ((l32 & 1) << 4)) * 272 + ((n & ~1) * 2));

    // fp32 recurrence state (C layout, f32x2 pairs p=(r0/2): {even r, odd r})
    f32x2 xprev2[8];
    #pragma unroll
    for (int p = 0; p < 8; ++p) xprev2[p] = (f32x2){0.f, 0.f};
#define XV(k) ((k) & 1 ? xprev2[(k) >> 1].y : xprev2[(k) >> 1].x)

    // ---- ping-pong current-step globals: set A = even t, set B = odd t ----
    uint4 svA0, svA1, svB0, svB1;      // 16 bf16 of s_t[gb][gm..gm+15]
    float skvA, skvB;
    float wsv[16];
    {
        const char* pS = (const char*)sT2 + soffB;
        svA0 = *(const uint4*)(pS); svA1 = *(const uint4*)(pS + 16);
        skvA = *(const float*)(SKj + koffB);
        const char* pW = (const char*)WsT;
        #pragma unroll
        for (int r = 0; r < 16; ++r) wsv[r] = *(const float*)(pW + woffB[r]);
    }
    __syncthreads();

    float inv_s = 1.f;                   // true mem = inv_s * bf16(state)

#define SCAN_STEP(T_CUR, Sc0,Sc1,SKc, Sn0,Sn1,SKn)                             \
    {                                                                          \
        const int tn = (T_CUR < 127) ? (T_CUR) + 1 : 127;                      \
        /* prefetch t+1 sv/skv at TOP: full-step vmcnt cover */                \
        {                                                                      \
            const char* pS = (const char*)sT2 + (size_t)tn * 16384 + soffB;    \
            Sn0 = *(const uint4*)(pS); Sn1 = *(const uint4*)(pS + 16);         \
            SKn = *(const float*)(SKj + (size_t)tn * 256 + koffB);             \
        }                                                                      \
        /* gate: g[b] = sigmoid(inv*dot(s_t[b],mem[b]) + SK[j][t][b]) */       \
        {                                                                      \
            const uint4* u4 = (const uint4*)(AB + gb * 136 + gm);              \
            const uint4 w0 = u4[0], w1 = u4[1];                                \
            float d0 = dot2bf(w0.x, Sc0.x, 0.f);                               \
            float d1 = dot2bf(w0.y, Sc0.y, 0.f);                               \
            float d2 = dot2bf(w0.z, Sc0.z, 0.f);                               \
            float d3 = dot2bf(w0.w, Sc0.w, 0.f);                               \
            d0 = dot2bf(w1.x, Sc1.x, d0);                                      \
            d1 = dot2bf(w1.y, Sc1.y, d1);                                      \
            d2 = dot2bf(w1.z, Sc1.z, d2);                                      \
            d3 = dot2bf(w1.w, Sc1.w, d3);                                      \
            float dg = (d0 + d1) + (d2 + d3);                                  \
            dg = dpp_add0<0x111>(dg);  /* row_shr:1 */                         \
            dg = dpp_add0<0x112>(dg);  /* row_shr:2 */                         \
            dg = dpp_add0<0x114>(dg);  /* row_shr:4 -> lanes 7 mod 8 */        \
            if ((tid & 7) == 7) {                                              \
                const float e = __expf(-(inv_s * dg + SKc));                   \
                g_l[gb] = __builtin_amdgcn_rcpf(1.f + e);                      \
            }                                                                  \
        }                                                                      \
        /* MFMA: acc = state(32b x 128m) . Uw(32n x 128m)^T */                 \
        f32x16 acc0 = {0.f,0.f,0.f,0.f,0.f,0.f,0.f,0.f,                        \
                       0.f,0.f,0.f,0.f,0.f,0.f,0.f,0.f};                       \
        f32x16 acc1 = acc0;                                                    \
        {                                                                      \
            const unsigned short* arow = AB + (bt2*32 + l32) * 136 + q * 8;    \
            _Pragma("unroll")                                                  \
            for (int kc = 0; kc < 8; ++kc) {                                   \
                const bf16x8 a = *(const bf16x8*)(arow + kc * 16);             \
                if (kc & 1) acc1 = __builtin_amdgcn_mfma_f32_32x32x16_bf16(a, b_h[kc], acc1, 0, 0, 0); \
                else        acc0 = __builtin_amdgcn_mfma_f32_32x32x16_bf16(a, b_h[kc], acc0, 0, 0, 0); \
            }                                                                  \
            acc0 += acc1;  /* merge before B1 (vector add -> v_pk_add_f32) */  \
        }                                                                      \
        LDS_BARRIER();   /* B1: AB reads complete; g_l visible */              \
        /* update owned (b, n) cells in C layout — packed f32 pairs */         \
        const float4 gA = *(const float4*)(g_l + bt2*32 + 4*q + 0);            \
        const float4 gB = *(const float4*)(g_l + bt2*32 + 4*q + 8);            \
        const float4 gC = *(const float4*)(g_l + bt2*32 + 4*q + 16);           \
        const float4 gD = *(const float4*)(g_l + bt2*32 + 4*q + 24);           \
        const f32x2 g2[8] = {{gA.x,gA.y},{gA.z,gA.w},{gB.x,gB.y},{gB.z,gB.w},  \
                             {gC.x,gC.y},{gC.z,gC.w},{gD.x,gD.y},{gD.z,gD.w}}; \
        const f32x2 inv2 = {inv_s, inv_s};                                     \
        const f32x2 ub2  = {ubv, ubv};                                         \
        f32x2 ssqv = {0.f, 0.f};                                               \
        _Pragma("unroll")                                                      \
        for (int p = 0; p < 8; ++p) {                                          \
            const f32x2 am = {acc0[2*p], acc0[2*p+1]};                         \
            const f32x2 wu = (f32x2){wsv[2*p], wsv[2*p+1]} + ub2;              \
            f32x2 hr = pkfma(inv2, am, wu);                                    \
            hr = pkmax0(hr);                              /* h_cand */         \
            const f32x2 x = pkfma(inv2, xprev2[p], hr * g2[p]);                \
            xprev2[p] = x;                                /* fp32 recurrence */\
            ssqv = pkfma(x, x, ssqv);                                          \
        }                                                                      \
        /* paired state write-back: 8x ds_write_b32 (R23-proven pack) */       \
        _Pragma("unroll")                                                      \
        for (int i = 0; i < 8; ++i) {                                          \
            const float xa = XV(i);                                            \
            const float xb = XV(i + 8);                                        \
            const float sa = dpp_xor1_move(xa);                                \
            const float sb = dpp_xor1_move(xb);                                \
            const float lo = evenl ? xa : sb;                                  \
            const float hi = evenl ? sa : xb;                                  \
            wdst[((i & 3) + 8 * (i >> 2)) * 68] = packtr(lo, hi);              \
        }                                                                      \
        /* wsv refetch for t+1 (use point is next update: ~1-step cover) */    \
        {                                                                      \
            const char* pW = (const char*)WsT + (size_t)tn * 32768;            \
            _Pragma("unroll")                                                  \
            for (int r = 0; r < 16; ++r)                                       \
                wsv[r] = *(const float*)(pW + woffB[r]);                       \
        }                                                                      \
        /* ssq reduce: 6-op DPP chain, lane 63 holds the wave total */         \
        float ssq = ssqv.x + ssqv.y;                                           \
        ssq = dpp_add0<0x111>(ssq);    /* row_shr:1 */                         \
        ssq = dpp_add0<0x112>(ssq);    /* row_shr:2 */                         \
        ssq = dpp_add0<0x114>(ssq);    /* row_shr:4 */                         \
        ssq = dpp_add0<0x118>(ssq);    /* row_shr:8 -> lane15 of each row */   \
        ssq = dpp_add0<0x142>(ssq);    /* row_bcast:15 -> lane31/63 combine */ \
        ssq = dpp_add0<0x143>(ssq);    /* row_bcast:31 -> lane63 total */      \
        if (lane == 63) wred[wave] = ssq;                                      \
        LDS_BARRIER();   /* B2: AB writes + wred visible (loads in flight) */  \
        const float4 w0 = *(const float4*)(wred);                              \
        const float4 w1 = *(const float4*)(wred + 4);                          \
        const float4 ws4 = w0 + w1;                                            \
        inv_s = __builtin_amdgcn_rsqf((ws4.x + ws4.y) + (ws4.z + ws4.w));      \
    }

    for (int t = 0; t < 128; t += 2) {
        SCAN_STEP(t,     svA0,svA1,skvA, svB0,svB1,skvB)
        SCAN_STEP(t + 1, svB0,svB1,skvB, svA0,svA1,skvA)
    }
#undef SCAN_STEP

    // ---- h = inv * state (fp32 path), layout (b, j, m) ----
    #pragma unroll
    for (int r = 0; r < 16; ++r) {
        const int brow = bt2*32 + 4*q + (r & 3) + 8*(r >> 2);
        h_out[(brow*20 + j)*128 + n] = inv_s * XV(r);
    }
#undef XV
}

// ---------------------------------------------------------------- final
__global__ __launch_bounds__(128) void final_kernel(
    const float* __restrict__ h, const float* __restrict__ qv,
    const float* __restrict__ a1v, const float* __restrict__ a2v,
    const float* __restrict__ Hw, const float* __restrict__ Hb,
    float* __restrict__ out)
{
    const int b   = blockIdx.x;
    const int tid = threadIdx.x;    // 128
    __shared__ float hb[20][128];
    __shared__ float ql[128];
    __shared__ float ul[128];
    __shared__ float pl[20];
    __shared__ float lgt[20];
    __shared__ float red1[2], red2[2];

    for (int jj = 0; jj < 20; ++jj) hb[jj][tid] = h[(b*20+jj)*128 + tid];
    ql[tid] = qv[b*128 + tid];
    __syncthreads();
    if (tid < 20) {
        float d = 0.f;
        for (int m = 0; m < 128; ++m) d += hb[tid][m] * ql[m];
        lgt[tid] = d;
    }
    __syncthreads();
    if (tid == 0) {
        float mx = lgt[0];
        for (int jj = 1; jj < 20; ++jj) mx = fmaxf(mx, lgt[jj]);
        float s = 0.f;
        for (int jj = 0; jj < 20; ++jj) { const float e = expf(lgt[jj]-mx); pl[jj] = e; s += e; }
        const float is = 1.f / s;
        for (int jj = 0; jj < 20; ++jj) pl[jj] *= is;
    }
    __syncthreads();
    float u = 0.f;
    for (int jj = 0; jj < 20; ++jj) u += pl[jj] * hb[jj][tid];
    ul[tid] = u;
    __syncthreads();
    float acc = ql[tid] + Hb[tid];
    const float4* hwr = (const float4*)(Hw + tid*128);
    for (int m4 = 0; m4 < 32; ++m4) {
        const float4 w = hwr[m4];
        acc += ul[m4*4]*w.x + ul[m4*4+1]*w.y + ul[m4*4+2]*w.z + ul[m4*4+3]*w.w;
    }
    const float r  = fmaxf(acc, 0.f);
    float y1 = r * a1v[b*128+tid];
    float y2 = r * a2v[b*128+tid];
    #pragma unroll
    for (int mask = 1; mask < 64; mask <<= 1) {
        y1 += __shfl_xor(y1, mask, 64);
        y2 += __shfl_xor(y2, mask, 64);
    }
    if ((tid & 63) == 0) { red1[tid>>6] = y1; red2[tid>>6] = y2; }
    __syncthreads();
    if (tid == 0) {
        const float z1 = red1[0] + red1[1];
        const float z2 = red2[0] + red2[1];
        const float mx = fmaxf(z1, z2);
        const float e1 = expf(z1-mx), e2 = expf(z2-mx);
        const float s  = e1 + e2;
        out[b*2+0] = e1 / s;
        out[b*2+1] = e2 / s;
    }
}

// ---------------------------------------------------------------- launch
extern "C" void kernel_launch(void* const* d_in, const int* in_sizes, int n_in,
                              void* d_out, int out_size, void* d_ws, size_t ws_size,
                              hipStream_t stream)
{
    const int*   ids  = (const int*)  d_in[0];
    const int*   ques = (const int*)  d_in[1];
    const int*   ans  = (const int*)  d_in[2];
    const float* E    = (const float*)d_in[3];
    const float* Uw   = (const float*)d_in[4];
    const float* Ubv  = (const float*)d_in[5];
    const float* Vw   = (const float*)d_in[6];
    const float* Vb   = (const float*)d_in[7];
    const float* Ww   = (const float*)d_in[8];
    const float* Wb   = (const float*)d_in[9];
    const float* sk   = (const float*)d_in[10];
    const float* Hw   = (const float*)d_in[11];
    const float* Hb   = (const float*)d_in[12];

    // workspace (floats): sT2 bf16[1048576] = 524288 floats | WsT 1048576 |
    //   vkey 2560 | qv/a1v/a2v 3*8192 | h 163840 | SK 163840   (~7.7 MB)
    float* ws   = (float*)d_ws;
    unsigned short* sT2 = (unsigned short*)ws;        // 1048576 ushort = 524288 floats
    float* WsT  = ws    + 524288;
    float* vkey = WsT   + 1048576;
    float* qv   = vkey  + 2560;
    float* a1v  = qv    + 8192;
    float* a2v  = a1v   + 8192;
    float* h    = a2v   + 8192;
    float* SK   = h     + 163840;

    prep_kernel<<<1108, 128, 0, stream>>>(ids, ques, ans, E, Ww, Wb, Vw, Vb, sk,
                                          sT2, WsT, vkey, qv, a1v, a2v, SK);
    scan_kernel<<<20, 512, 0, stream>>>(sT2, WsT, vkey, Uw, Ubv, SK, h);
    final_kernel<<<64, 128, 0, stream>>>(h, qv, a1v, a2v, Hw, Hb, (float*)d_out);
}